// Round 11
// baseline (1033.157 us; speedup 1.0000x reference)
//
#include <hip/hip_runtime.h>

// SpikingNetwork: B=128 T=128 I=1024 H1=2048 H2=2048 O=512
// R11: B-operand in registers via PLAIN C++ vector loads (compiler-managed
//   deps — read-only data needs no manual sync); LDS = A only (2x32KB dbuf,
//   gld_lds staged, row-XOR swizzle, proven R8 mechanics). Manual ledger only
//   where proven: VMC(0)+BAR at p2 (A-stage visible), lgkm 4-deep ds_read
//   pipe, BAR at tile end (WAR). Four-quarter fused LIF epilogue (64x258).
// Numerics: GEMM1 3-term split-bf16 (K'=3072), GEMM2 hi-only (K'=2048,
//   s1 binary exact), GEMM3 split-K atomic. f32 accumulate.

typedef unsigned long long u64;
typedef __attribute__((ext_vector_type(4))) float f32x4;
typedef __attribute__((ext_vector_type(8))) short bf16x8;

__device__ __forceinline__ unsigned short f2bf(float f) {
  unsigned u = __float_as_uint(f);
  u += 0x7fff + ((u >> 16) & 1);   // RNE
  return (unsigned short)(u >> 16);
}
__device__ __forceinline__ float bf2f(unsigned short h) {
  return __uint_as_float(((unsigned)h) << 16);
}
__device__ __forceinline__ void gld_lds16(const unsigned short* g, unsigned short* l) {
  __builtin_amdgcn_global_load_lds((const __attribute__((address_space(1))) void*)g,
                                   (__attribute__((address_space(3))) void*)l, 16, 0, 0);
}

// src: R x K f32 (K = 1<<lgK) -> dst: R x 2K bf16 rows [hi | lo], 4 elem/thread
__global__ void k_split4(const float4* __restrict__ src, unsigned short* __restrict__ dst,
                         int lgK, size_t total4) {
  size_t i = (size_t)blockIdx.x * 256 + threadIdx.x;
  if (i >= total4) return;
  const int K = 1 << lgK;
  size_t e = i << 2;
  size_t r = e >> lgK;
  int k = (int)(e & (size_t)(K - 1));
  float4 f = src[i];
  unsigned short h0 = f2bf(f.x), h1 = f2bf(f.y), h2 = f2bf(f.z), h3 = f2bf(f.w);
  unsigned short l0 = f2bf(f.x - bf2f(h0)), l1 = f2bf(f.y - bf2f(h1));
  unsigned short l2 = f2bf(f.z - bf2f(h2)), l3 = f2bf(f.w - bf2f(h3));
  size_t o = (r << (lgK + 1)) + (size_t)k;
  *(u64*)(dst + o)     = (u64)h0 | ((u64)h1 << 16) | ((u64)h2 << 32) | ((u64)h3 << 48);
  *(u64*)(dst + o + K) = (u64)l0 | ((u64)l1 << 16) | ((u64)l2 << 32) | ((u64)l3 << 48);
}

// 4x ds_read_b128 from base + m*2048 (m-th 16-row fragment group, 128B rows)
#define DSR4(D, BASE)                                                          \
  do {                                                                         \
    asm volatile("ds_read_b128 %0, %1" : "=v"(D[0]) : "v"(BASE));              \
    asm volatile("ds_read_b128 %0, %1 offset:2048" : "=v"(D[1]) : "v"(BASE));  \
    asm volatile("ds_read_b128 %0, %1 offset:4096" : "=v"(D[2]) : "v"(BASE));  \
    asm volatile("ds_read_b128 %0, %1 offset:6144" : "=v"(D[3]) : "v"(BASE));  \
  } while (0)
#define WAITL(N)                                                               \
  do {                                                                         \
    asm volatile("s_waitcnt lgkmcnt(" #N ")" ::: "memory");                    \
    __builtin_amdgcn_sched_barrier(0);                                         \
  } while (0)
#define VMC(N)                                                                 \
  do {                                                                         \
    asm volatile("s_waitcnt vmcnt(" #N ")" ::: "memory");                      \
    __builtin_amdgcn_sched_barrier(0);                                         \
  } while (0)
#define BAR() __builtin_amdgcn_s_barrier()
#define SP1() __builtin_amdgcn_s_setprio(1)
#define SP0() __builtin_amdgcn_s_setprio(0)
#define MFMA16(MH, AF, BG)                                                     \
  _Pragma("unroll")                                                            \
  for (int m = 0; m < 4; ++m)                                                  \
    _Pragma("unroll")                                                          \
    for (int n = 0; n < 4; ++n)                                                \
      acc[(MH)*4 + m][n] = __builtin_amdgcn_mfma_f32_16x16x32_bf16(            \
          AF[m], BG[n], acc[(MH)*4 + m][n], 0, 0, 0);

// B frag loads: plain C++ 16B vector loads from read-only W (compiler emits
// global_load_dwordx4 + its own counted vmcnt before the consuming MFMA).
#define LOAD_B(TT, D, KS)                                                      \
  do {                                                                         \
    if ((TT) < NKT) {                                                          \
      const int kb_ = (TT) * 64;                                               \
      const int boff_ =                                                        \
          (LAYER == 1) ? ((kb_ < 2048) ? kb_ : kb_ - 2048) : kb_;              \
      _Pragma("unroll")                                                        \
      for (int n = 0; n < 4; ++n)                                              \
        D[n] = *(const bf16x8*)(Bw + (size_t)(browB[n] + boff_ + (KS) * 32));  \
    }                                                                          \
  } while (0)

// Fused pipelined GEMM + LIF. Block tile 256x256 (2 batches' full time
// series x 256 cols). LAYER 1: NKT=48 (3-term); LAYER 2: NKT=32 (hi-only).
template <int LAYER>
__global__ __launch_bounds__(512, 2)
void k_gemm_lif(const unsigned short* __restrict__ A,
                const unsigned short* __restrict__ Bw,
                const float* __restrict__ bias,
                unsigned short* __restrict__ out, int b0) {
  __shared__ __align__(128) char lds[66048];   // 2x32KB A-slots; epi 64x258 f32
  const int NKT = (LAYER == 1) ? 48 : 32;
  const int ldB = (LAYER == 1) ? 2048 : 4096;
  const int tid  = threadIdx.x;
  const int lane = tid & 63;
  const int w    = tid >> 6;                 // 0..7
  const int wm = w >> 2, wn = w & 3;         // 2M x 4N waves
  const int wr = wm * 128, wc = wn * 64;     // wave tile 128x64
  const int lrow = lane & 15, t4 = lane >> 4;
  const int brow = blockIdx.x * 256, bcol = blockIdx.y * 256;

  f32x4 acc[8][4];
#pragma unroll
  for (int m = 0; m < 8; ++m)
#pragma unroll
    for (int n = 0; n < 4; ++n) acc[m][n] = (f32x4){0.f, 0.f, 0.f, 0.f};

  // A-staging geometry (K-loop invariant): 2048 16B chunks, 4/thread.
  // Global source col pre-swizzled (chunk ^ row&7); LDS dest linear.
  int voffA[4];
  unsigned dstA[4];
#pragma unroll
  for (int j = 0; j < 4; ++j) {
    const int c = tid + j * 512;
    const int r = c >> 3;
    const int scol = ((c & 7) ^ (r & 7)) * 8;
    voffA[j] = (brow + r) * 2048 + scol;
    dstA[j] = (unsigned)c * 16;
  }
  // B per-lane element offsets (row base + t4 chunk), one per n-frag.
  int browB[4];
#pragma unroll
  for (int n = 0; n < 4; ++n)
    browB[n] = (bcol + wc + n * 16 + lrow) * ldB + t4 * 8;

  auto stage_tile = [&](int tt) {
    if (tt >= NKT) return;
    const int kb = tt * 64;
    const int aoff = (LAYER == 1) ? ((kb < 1024) ? kb : kb - 1024) : kb;
    const unsigned short* Ap = A + aoff;
#pragma unroll
    for (int j = 0; j < 4; ++j)
      gld_lds16(Ap + voffA[j],
                (unsigned short*)(lds + (tt & 1) * 32768 + dstA[j]));
  };

  // LDS fragment-read addressing (row&7 == lrow&7 for all frag rows).
  const unsigned ldsb = (unsigned)(size_t)(__attribute__((address_space(3))) char*)lds;
  const unsigned cA  = (unsigned)((wr + lrow) * 128);
  const unsigned ch0 = (unsigned)(((t4) ^ (lrow & 7)) * 16);
  const unsigned ch1 = (unsigned)(((4 + t4) ^ (lrow & 7)) * 16);

  bf16x8 afA[4], afB[4], bgE[4], bgO[4], bg1[4];

  // prologue: stage A(0); load B(0,ks0) -> bgE; drain; first A-frag reads
  stage_tile(0);
  LOAD_B(0, bgE, 0);
  VMC(0);
  BAR();
  DSR4(afA, ldsb + cA + ch0);

#define TILE_BODY(T, BGC, BGN)                                                 \
  {                                                                            \
    const int tt = (T);                                                        \
    const unsigned sA  = ldsb + (unsigned)((tt & 1) * 32768);                  \
    const unsigned sAn = ldsb + (unsigned)(((tt + 1) & 1) * 32768);            \
    stage_tile(tt + 1);                                                        \
    LOAD_B(tt, bg1, 1);             /* B ks1 of this tile */                   \
    LOAD_B(tt + 1, BGN, 0);         /* B ks0 of next tile */                   \
    /* p0 */                                                                   \
    DSR4(afB, sA + cA + 8192 + ch0);                                           \
    WAITL(4);                                                                  \
    SP1(); MFMA16(0, afA, BGC); SP0();                                         \
    /* p1 */                                                                   \
    DSR4(afA, sA + cA + ch1);                                                  \
    WAITL(4);                                                                  \
    SP1(); MFMA16(1, afB, BGC); SP0();                                         \
    /* p2 */                                                                   \
    DSR4(afB, sA + cA + 8192 + ch1);                                           \
    WAITL(4);                                                                  \
    SP1(); MFMA16(0, afA, bg1); SP0();                                         \
    VMC(0);                         /* A-stage(t+1) drained (issued ~3 ph ago) */ \
    BAR();                          /* ...and visible to all waves */          \
    /* p3 */                                                                   \
    if (tt + 1 < NKT) { DSR4(afA, sAn + cA + ch0); WAITL(4); }                 \
    else              { WAITL(0); }                                            \
    SP1(); MFMA16(1, afB, bg1); SP0();                                         \
    BAR();                          /* slot-t WAR safe (reads lgkm-complete) */\
  }

#pragma unroll 1
  for (int t = 0; t < NKT; t += 2) {
    TILE_BODY(t, bgE, bgO);
    TILE_BODY(t + 1, bgO, bgE);
  }
#undef TILE_BODY

  // ---- fused LIF epilogue: four 64-row quarters via 64x258 f32 LDS ----
  float* Ct = (float*)lds;
  const int colT = tid & 255;
  const float bs = bias[bcol + colT];
  float v = 0.f;
  int cnt = 0;
#pragma unroll
  for (int q = 0; q < 4; ++q) {
    const int b = q >> 1, h = q & 1;           // batch, time-half
    __syncthreads();
    if (wm == b) {                              // waves owning this batch dump
#pragma unroll
      for (int mm = 0; mm < 4; ++mm) {
        const int m = h * 4 + mm;              // frag m covers t = m*16..+15
#pragma unroll
        for (int n = 0; n < 4; ++n) {
          const int lr  = mm * 16 + t4 * 4;
          const int col = wc + n * 16 + lrow;
#pragma unroll
          for (int r = 0; r < 4; ++r) Ct[(lr + r) * 258 + col] = acc[m][n][r];
        }
      }
    }
    __syncthreads();
    if (tid < 256) {
      if (LAYER == 1) {
        unsigned short* sp =
            out + (size_t)(brow + b * 128 + h * 64) * 2048 + bcol + colT;
#pragma unroll 4
        for (int tl = 0; tl < 64; ++tl) {
          const float xx = Ct[tl * 258 + colT] + bs;
          v = 0.9f * xx + v - ((xx > 1.0f) ? 1.0f : 0.0f);
          sp[(size_t)tl * 2048] =
              (v > 1.0f) ? (unsigned short)0x3F80 : (unsigned short)0;
        }
      } else {
#pragma unroll 4
        for (int tl = 0; tl < 64; ++tl) {
          const float xx = Ct[tl * 258 + colT] + bs;
          v = 0.9f * xx + v - ((xx > 1.0f) ? 1.0f : 0.0f);
          cnt += (v > 1.0f);
        }
      }
      if (h == 1) {                             // end of a batch's time series
        if (LAYER == 2)
          out[(size_t)(b0 + 2 * blockIdx.x + b) * 2048 + bcol + colT] =
              f2bf((float)cnt * 0.0078125f);
        v = 0.f; cnt = 0;
      }
    }
  }
}

// out(128x512) += ACC(128x2048 bf16) @ Wocat^T over K-slice z*256..+256, atomic
__global__ void k_gemm3(const unsigned short* __restrict__ A,
                        const unsigned short* __restrict__ B,
                        float* __restrict__ C) {
  __shared__ __align__(16) unsigned short Asm[128 * 64];
  __shared__ __align__(16) unsigned short Bsm[128 * 64];
  const int tid  = threadIdx.x;
  const int bcol = blockIdx.y * 128;
  const int k0   = blockIdx.z * 256;
  const int lane = tid & 63;
  const int w    = tid >> 6;
  const int wr = (w >> 1) * 64, wc = (w & 1) * 64;
  const int lrow = lane & 15, lk = (lane >> 4) * 8;

  f32x4 acc[4][4];
#pragma unroll
  for (int m = 0; m < 4; ++m)
#pragma unroll
    for (int n = 0; n < 4; ++n) acc[m][n] = (f32x4){0.f, 0.f, 0.f, 0.f};

  for (int kt = 0; kt < 4; ++kt) {
    const int kb = k0 + kt * 64;
#pragma unroll
    for (int i = 0; i < 4; ++i) {
      int c = tid + i * 256;
      int row = c >> 3, kc = (c & 7) * 8;
      gld_lds16(A + (size_t)row * 2048 + (kb & 2047) + kc, &Asm[c * 8]);
      gld_lds16(B + (size_t)(bcol + row) * 4096 + kb + kc, &Bsm[c * 8]);
    }
    __syncthreads();
#pragma unroll
    for (int ks = 0; ks < 2; ++ks) {
      bf16x8 af[4], bg[4];
#pragma unroll
      for (int m = 0; m < 4; ++m)
        af[m] = *(const bf16x8*)&Asm[(wr + m * 16 + lrow) * 64 + ks * 32 + lk];
#pragma unroll
      for (int n = 0; n < 4; ++n)
        bg[n] = *(const bf16x8*)&Bsm[(wc + n * 16 + lrow) * 64 + ks * 32 + lk];
#pragma unroll
      for (int m = 0; m < 4; ++m)
#pragma unroll
        for (int n = 0; n < 4; ++n)
          acc[m][n] = __builtin_amdgcn_mfma_f32_16x16x32_bf16(af[m], bg[n], acc[m][n], 0, 0, 0);
    }
    __syncthreads();
  }
#pragma unroll
  for (int m = 0; m < 4; ++m)
#pragma unroll
    for (int n = 0; n < 4; ++n) {
      int r0 = wr + m * 16 + (lane >> 4) * 4;
      int c0 = bcol + wc + n * 16 + (lane & 15);
#pragma unroll
      for (int r = 0; r < 4; ++r)
        atomicAdd(&C[(size_t)(r0 + r) * 512 + c0], acc[m][n][r]);
    }
}

__global__ void k_init_out(float* __restrict__ out, const float* __restrict__ bout) {
  int i = blockIdx.x * 256 + threadIdx.x;   // 128*512
  out[i] = bout[i & 511];
}

extern "C" void kernel_launch(void* const* d_in, const int* in_sizes, int n_in,
                              void* d_out, int out_size, void* d_ws, size_t ws_size,
                              hipStream_t stream) {
  const float* x    = (const float*)d_in[0];
  const float* W1   = (const float*)d_in[1];
  const float* b1   = (const float*)d_in[2];
  const float* W2   = (const float*)d_in[3];
  const float* b2   = (const float*)d_in[4];
  const float* Wout = (const float*)d_in[5];
  const float* bout = (const float*)d_in[6];
  float* out = (float*)d_out;
  (void)in_sizes; (void)n_in; (void)out_size;

  char* ws = (char*)d_ws;
  size_t off = 0;
  auto alloc = [&](size_t bytes) -> void* {
    void* p = ws + off;
    off += (bytes + 255) & ~(size_t)255;
    return p;
  };
  unsigned short* W1cat = (unsigned short*)alloc((size_t)2048 * 2048 * 2);  // 8 MiB
  unsigned short* W2cat = (unsigned short*)alloc((size_t)2048 * 4096 * 2);  // 16 MiB
  unsigned short* Wocat = (unsigned short*)alloc((size_t)512 * 4096 * 2);   // 4 MiB
  unsigned short* ACC   = (unsigned short*)alloc((size_t)128 * 2048 * 2);   // 0.5 MiB
  const size_t fixed = off;

  // largest row-chunk (multiple of 1024) whose Xcat+S1 fit in ws
  int rows_c = 16384;
  while (rows_c > 1024) {
    size_t per = 2 * (((size_t)rows_c * 2048 * 2 + 255) & ~(size_t)255);
    if (fixed + per <= ws_size) break;
    rows_c >>= 1;
  }
  unsigned short* Xcat = (unsigned short*)alloc((size_t)rows_c * 2048 * 2);
  unsigned short* S1c  = (unsigned short*)alloc((size_t)rows_c * 2048 * 2);

  // weight splits (once per call), 4 elem/thread
  k_split4<<<(2048 * 256 + 255) / 256, 256, 0, stream>>>((const float4*)W1, W1cat, 10,
                                                         (size_t)2048 * 256);
  k_split4<<<(2048 * 512 + 255) / 256, 256, 0, stream>>>((const float4*)W2, W2cat, 11,
                                                         (size_t)2048 * 512);
  k_split4<<<(512 * 512 + 255) / 256, 256, 0, stream>>>((const float4*)Wout, Wocat, 11,
                                                        (size_t)512 * 512);

  const int nch = 16384 / rows_c;
  for (int c = 0; c < nch; ++c) {
    k_split4<<<rows_c, 256, 0, stream>>>((const float4*)(x + (size_t)c * rows_c * 1024),
                                         Xcat, 10, (size_t)rows_c * 256);
    k_gemm_lif<1><<<dim3(rows_c / 256, 8), 512, 0, stream>>>(Xcat, W1cat, b1, S1c, 0);
    k_gemm_lif<2><<<dim3(rows_c / 256, 8), 512, 0, stream>>>(S1c, W2cat, b2, ACC,
                                                             c * (rows_c / 128));
  }
  k_init_out<<<256, 256, 0, stream>>>(out, bout);
  k_gemm3<<<dim3(1, 4, 16), 256, 0, stream>>>(ACC, Wocat, out);
}

// Round 12
// 581.884 us; speedup vs baseline: 1.7755x; 1.7755x over previous
//
#include <hip/hip_runtime.h>

// SpikingNetwork: B=128 T=128 I=1024 H1=2048 H2=2048 O=512
// R12: R11 (B-in-regs, correct) with the register spill fixed: only TWO
//   B buffers (bgA=ks0 cur, bgB=ks1 cur) with 2-phase load lead; no 2-tile
//   unroll. Arch-VGPR budget ~106 < 128 cap (acc 128 in AGPR half).
//   LDS = A only (2x32KB dbuf, gld_lds, row-XOR swizzle). Manual ledger
//   only where proven: VMC(0)+BAR at p2 (A-stage visible), lgkm 4-deep
//   ds_read pipe, BAR at tile end (WAR). Plain C++ B loads (compiler
//   inserts counted vmcnt before consuming MFMA). Four-quarter epilogue.
// Numerics: GEMM1 3-term split-bf16 (K'=3072), GEMM2 hi-only (K'=2048,
//   s1 binary exact), GEMM3 split-K atomic. f32 accumulate.

typedef unsigned long long u64;
typedef __attribute__((ext_vector_type(4))) float f32x4;
typedef __attribute__((ext_vector_type(8))) short bf16x8;

__device__ __forceinline__ unsigned short f2bf(float f) {
  unsigned u = __float_as_uint(f);
  u += 0x7fff + ((u >> 16) & 1);   // RNE
  return (unsigned short)(u >> 16);
}
__device__ __forceinline__ float bf2f(unsigned short h) {
  return __uint_as_float(((unsigned)h) << 16);
}
__device__ __forceinline__ void gld_lds16(const unsigned short* g, unsigned short* l) {
  __builtin_amdgcn_global_load_lds((const __attribute__((address_space(1))) void*)g,
                                   (__attribute__((address_space(3))) void*)l, 16, 0, 0);
}

// src: R x K f32 (K = 1<<lgK) -> dst: R x 2K bf16 rows [hi | lo], 4 elem/thread
__global__ void k_split4(const float4* __restrict__ src, unsigned short* __restrict__ dst,
                         int lgK, size_t total4) {
  size_t i = (size_t)blockIdx.x * 256 + threadIdx.x;
  if (i >= total4) return;
  const int K = 1 << lgK;
  size_t e = i << 2;
  size_t r = e >> lgK;
  int k = (int)(e & (size_t)(K - 1));
  float4 f = src[i];
  unsigned short h0 = f2bf(f.x), h1 = f2bf(f.y), h2 = f2bf(f.z), h3 = f2bf(f.w);
  unsigned short l0 = f2bf(f.x - bf2f(h0)), l1 = f2bf(f.y - bf2f(h1));
  unsigned short l2 = f2bf(f.z - bf2f(h2)), l3 = f2bf(f.w - bf2f(h3));
  size_t o = (r << (lgK + 1)) + (size_t)k;
  *(u64*)(dst + o)     = (u64)h0 | ((u64)h1 << 16) | ((u64)h2 << 32) | ((u64)h3 << 48);
  *(u64*)(dst + o + K) = (u64)l0 | ((u64)l1 << 16) | ((u64)l2 << 32) | ((u64)l3 << 48);
}

// 4x ds_read_b128 from base + m*2048 (m-th 16-row fragment group, 128B rows)
#define DSR4(D, BASE)                                                          \
  do {                                                                         \
    asm volatile("ds_read_b128 %0, %1" : "=v"(D[0]) : "v"(BASE));              \
    asm volatile("ds_read_b128 %0, %1 offset:2048" : "=v"(D[1]) : "v"(BASE));  \
    asm volatile("ds_read_b128 %0, %1 offset:4096" : "=v"(D[2]) : "v"(BASE));  \
    asm volatile("ds_read_b128 %0, %1 offset:6144" : "=v"(D[3]) : "v"(BASE));  \
  } while (0)
#define WAITL(N)                                                               \
  do {                                                                         \
    asm volatile("s_waitcnt lgkmcnt(" #N ")" ::: "memory");                    \
    __builtin_amdgcn_sched_barrier(0);                                         \
  } while (0)
#define VMC(N)                                                                 \
  do {                                                                         \
    asm volatile("s_waitcnt vmcnt(" #N ")" ::: "memory");                      \
    __builtin_amdgcn_sched_barrier(0);                                         \
  } while (0)
#define BAR() __builtin_amdgcn_s_barrier()
#define SP1() __builtin_amdgcn_s_setprio(1)
#define SP0() __builtin_amdgcn_s_setprio(0)
#define MFMA16(MH, AF, BG)                                                     \
  _Pragma("unroll")                                                            \
  for (int m = 0; m < 4; ++m)                                                  \
    _Pragma("unroll")                                                          \
    for (int n = 0; n < 4; ++n)                                                \
      acc[(MH)*4 + m][n] = __builtin_amdgcn_mfma_f32_16x16x32_bf16(            \
          AF[m], BG[n], acc[(MH)*4 + m][n], 0, 0, 0);

// B frag loads: plain C++ 16B vector loads from read-only W (compiler emits
// global_load_dwordx4 + its own counted vmcnt before the consuming MFMA).
#define LOAD_B(TT, D, KS)                                                      \
  do {                                                                         \
    if ((TT) < NKT) {                                                          \
      const int kb_ = (TT) * 64;                                               \
      const int boff_ =                                                        \
          (LAYER == 1) ? ((kb_ < 2048) ? kb_ : kb_ - 2048) : kb_;              \
      _Pragma("unroll")                                                        \
      for (int n = 0; n < 4; ++n)                                              \
        D[n] = *(const bf16x8*)(Bw + (size_t)(browB[n] + boff_ + (KS) * 32));  \
    }                                                                          \
  } while (0)

// Fused pipelined GEMM + LIF. Block tile 256x256 (2 batches' full time
// series x 256 cols). LAYER 1: NKT=48 (3-term); LAYER 2: NKT=32 (hi-only).
template <int LAYER>
__global__ __launch_bounds__(512, 2)
void k_gemm_lif(const unsigned short* __restrict__ A,
                const unsigned short* __restrict__ Bw,
                const float* __restrict__ bias,
                unsigned short* __restrict__ out, int b0) {
  __shared__ __align__(128) char lds[66048];   // 2x32KB A-slots; epi 64x258 f32
  const int NKT = (LAYER == 1) ? 48 : 32;
  const int ldB = (LAYER == 1) ? 2048 : 4096;
  const int tid  = threadIdx.x;
  const int lane = tid & 63;
  const int w    = tid >> 6;                 // 0..7
  const int wm = w >> 2, wn = w & 3;         // 2M x 4N waves
  const int wr = wm * 128, wc = wn * 64;     // wave tile 128x64
  const int lrow = lane & 15, t4 = lane >> 4;
  const int brow = blockIdx.x * 256, bcol = blockIdx.y * 256;

  f32x4 acc[8][4];
#pragma unroll
  for (int m = 0; m < 8; ++m)
#pragma unroll
    for (int n = 0; n < 4; ++n) acc[m][n] = (f32x4){0.f, 0.f, 0.f, 0.f};

  // A-staging geometry (K-loop invariant): 2048 16B chunks, 4/thread.
  // Global source col pre-swizzled (chunk ^ row&7); LDS dest linear.
  int voffA[4];
  unsigned dstA[4];
#pragma unroll
  for (int j = 0; j < 4; ++j) {
    const int c = tid + j * 512;
    const int r = c >> 3;
    const int scol = ((c & 7) ^ (r & 7)) * 8;
    voffA[j] = (brow + r) * 2048 + scol;
    dstA[j] = (unsigned)c * 16;
  }
  // B per-lane element offsets (row base + t4 chunk), one per n-frag.
  int browB[4];
#pragma unroll
  for (int n = 0; n < 4; ++n)
    browB[n] = (bcol + wc + n * 16 + lrow) * ldB + t4 * 8;

  auto stage_tile = [&](int tt) {
    if (tt >= NKT) return;
    const int kb = tt * 64;
    const int aoff = (LAYER == 1) ? ((kb < 1024) ? kb : kb - 1024) : kb;
    const unsigned short* Ap = A + aoff;
#pragma unroll
    for (int j = 0; j < 4; ++j)
      gld_lds16(Ap + voffA[j],
                (unsigned short*)(lds + (tt & 1) * 32768 + dstA[j]));
  };

  // LDS fragment-read addressing (row&7 == lrow&7 for all frag rows).
  const unsigned ldsb = (unsigned)(size_t)(__attribute__((address_space(3))) char*)lds;
  const unsigned cA  = (unsigned)((wr + lrow) * 128);
  const unsigned ch0 = (unsigned)(((t4) ^ (lrow & 7)) * 16);
  const unsigned ch1 = (unsigned)(((4 + t4) ^ (lrow & 7)) * 16);

  bf16x8 afA[4], afB[4], bgA[4], bgB[4];   // 64 arch VGPRs total

  // prologue: stage A(0); load B(0,ks0) -> bgA; drain; first A-frag reads
  stage_tile(0);
  LOAD_B(0, bgA, 0);
  VMC(0);
  BAR();
  DSR4(afA, ldsb + cA + ch0);

#pragma unroll 1
  for (int t = 0; t < NKT; ++t) {
    const unsigned sA  = ldsb + (unsigned)((t & 1) * 32768);
    const unsigned sAn = ldsb + (unsigned)(((t + 1) & 1) * 32768);
    stage_tile(t + 1);
    // p0: MFMA(MH0,ks0); load bgB=B(t,ks1) (used p2); read afB=MH1/ks0
    LOAD_B(t, bgB, 1);
    DSR4(afB, sA + cA + 8192 + ch0);
    WAITL(4);
    SP1(); MFMA16(0, afA, bgA); SP0();
    // p1: MFMA(MH1,ks0); read afA=MH0/ks1
    DSR4(afA, sA + cA + ch1);
    WAITL(4);
    SP1(); MFMA16(1, afB, bgA); SP0();
    // p2: MFMA(MH0,ks1); read afB=MH1/ks1; then A-stage(t+1) visible
    DSR4(afB, sA + cA + 8192 + ch1);
    WAITL(4);
    SP1(); MFMA16(0, afA, bgB); SP0();
    VMC(0);                      // A-stage(t+1) drained (issued ~3 ph ago)
    BAR();                       // ...and visible to all waves
    // p3: MFMA(MH1,ks1); load bgA=B(t+1,ks0) (used next p0); early A-read
    if (t + 1 < NKT) {
      LOAD_B(t + 1, bgA, 0);
      DSR4(afA, sAn + cA + ch0);
      WAITL(4);
    } else {
      WAITL(0);
    }
    SP1(); MFMA16(1, afB, bgB); SP0();
    BAR();                       // slot-t WAR safe (reads lgkm-complete)
  }

  // ---- fused LIF epilogue: four 64-row quarters via 64x258 f32 LDS ----
  float* Ct = (float*)lds;
  const int colT = tid & 255;
  const float bs = bias[bcol + colT];
  float v = 0.f;
  int cnt = 0;
#pragma unroll
  for (int q = 0; q < 4; ++q) {
    const int b = q >> 1, h = q & 1;           // batch, time-half
    __syncthreads();
    if (wm == b) {                              // waves owning this batch dump
#pragma unroll
      for (int mm = 0; mm < 4; ++mm) {
        const int m = h * 4 + mm;              // frag m covers t = m*16..+15
#pragma unroll
        for (int n = 0; n < 4; ++n) {
          const int lr  = mm * 16 + t4 * 4;
          const int col = wc + n * 16 + lrow;
#pragma unroll
          for (int r = 0; r < 4; ++r) Ct[(lr + r) * 258 + col] = acc[m][n][r];
        }
      }
    }
    __syncthreads();
    if (tid < 256) {
      if (LAYER == 1) {
        unsigned short* sp =
            out + (size_t)(brow + b * 128 + h * 64) * 2048 + bcol + colT;
#pragma unroll 4
        for (int tl = 0; tl < 64; ++tl) {
          const float xx = Ct[tl * 258 + colT] + bs;
          v = 0.9f * xx + v - ((xx > 1.0f) ? 1.0f : 0.0f);
          sp[(size_t)tl * 2048] =
              (v > 1.0f) ? (unsigned short)0x3F80 : (unsigned short)0;
        }
      } else {
#pragma unroll 4
        for (int tl = 0; tl < 64; ++tl) {
          const float xx = Ct[tl * 258 + colT] + bs;
          v = 0.9f * xx + v - ((xx > 1.0f) ? 1.0f : 0.0f);
          cnt += (v > 1.0f);
        }
      }
      if (h == 1) {                             // end of a batch's time series
        if (LAYER == 2)
          out[(size_t)(b0 + 2 * blockIdx.x + b) * 2048 + bcol + colT] =
              f2bf((float)cnt * 0.0078125f);
        v = 0.f; cnt = 0;
      }
    }
  }
}

// out(128x512) += ACC(128x2048 bf16) @ Wocat^T over K-slice z*256..+256, atomic
__global__ void k_gemm3(const unsigned short* __restrict__ A,
                        const unsigned short* __restrict__ B,
                        float* __restrict__ C) {
  __shared__ __align__(16) unsigned short Asm[128 * 64];
  __shared__ __align__(16) unsigned short Bsm[128 * 64];
  const int tid  = threadIdx.x;
  const int bcol = blockIdx.y * 128;
  const int k0   = blockIdx.z * 256;
  const int lane = tid & 63;
  const int w    = tid >> 6;
  const int wr = (w >> 1) * 64, wc = (w & 1) * 64;
  const int lrow = lane & 15, lk = (lane >> 4) * 8;

  f32x4 acc[4][4];
#pragma unroll
  for (int m = 0; m < 4; ++m)
#pragma unroll
    for (int n = 0; n < 4; ++n) acc[m][n] = (f32x4){0.f, 0.f, 0.f, 0.f};

  for (int kt = 0; kt < 4; ++kt) {
    const int kb = k0 + kt * 64;
#pragma unroll
    for (int i = 0; i < 4; ++i) {
      int c = tid + i * 256;
      int row = c >> 3, kc = (c & 7) * 8;
      gld_lds16(A + (size_t)row * 2048 + (kb & 2047) + kc, &Asm[c * 8]);
      gld_lds16(B + (size_t)(bcol + row) * 4096 + kb + kc, &Bsm[c * 8]);
    }
    __syncthreads();
#pragma unroll
    for (int ks = 0; ks < 2; ++ks) {
      bf16x8 af[4], bg[4];
#pragma unroll
      for (int m = 0; m < 4; ++m)
        af[m] = *(const bf16x8*)&Asm[(wr + m * 16 + lrow) * 64 + ks * 32 + lk];
#pragma unroll
      for (int n = 0; n < 4; ++n)
        bg[n] = *(const bf16x8*)&Bsm[(wc + n * 16 + lrow) * 64 + ks * 32 + lk];
#pragma unroll
      for (int m = 0; m < 4; ++m)
#pragma unroll
        for (int n = 0; n < 4; ++n)
          acc[m][n] = __builtin_amdgcn_mfma_f32_16x16x32_bf16(af[m], bg[n], acc[m][n], 0, 0, 0);
    }
    __syncthreads();
  }
#pragma unroll
  for (int m = 0; m < 4; ++m)
#pragma unroll
    for (int n = 0; n < 4; ++n) {
      int r0 = wr + m * 16 + (lane >> 4) * 4;
      int c0 = bcol + wc + n * 16 + (lane & 15);
#pragma unroll
      for (int r = 0; r < 4; ++r)
        atomicAdd(&C[(size_t)(r0 + r) * 512 + c0], acc[m][n][r]);
    }
}

__global__ void k_init_out(float* __restrict__ out, const float* __restrict__ bout) {
  int i = blockIdx.x * 256 + threadIdx.x;   // 128*512
  out[i] = bout[i & 511];
}

extern "C" void kernel_launch(void* const* d_in, const int* in_sizes, int n_in,
                              void* d_out, int out_size, void* d_ws, size_t ws_size,
                              hipStream_t stream) {
  const float* x    = (const float*)d_in[0];
  const float* W1   = (const float*)d_in[1];
  const float* b1   = (const float*)d_in[2];
  const float* W2   = (const float*)d_in[3];
  const float* b2   = (const float*)d_in[4];
  const float* Wout = (const float*)d_in[5];
  const float* bout = (const float*)d_in[6];
  float* out = (float*)d_out;
  (void)in_sizes; (void)n_in; (void)out_size;

  char* ws = (char*)d_ws;
  size_t off = 0;
  auto alloc = [&](size_t bytes) -> void* {
    void* p = ws + off;
    off += (bytes + 255) & ~(size_t)255;
    return p;
  };
  unsigned short* W1cat = (unsigned short*)alloc((size_t)2048 * 2048 * 2);  // 8 MiB
  unsigned short* W2cat = (unsigned short*)alloc((size_t)2048 * 4096 * 2);  // 16 MiB
  unsigned short* Wocat = (unsigned short*)alloc((size_t)512 * 4096 * 2);   // 4 MiB
  unsigned short* ACC   = (unsigned short*)alloc((size_t)128 * 2048 * 2);   // 0.5 MiB
  const size_t fixed = off;

  // largest row-chunk (multiple of 1024) whose Xcat+S1 fit in ws
  int rows_c = 16384;
  while (rows_c > 1024) {
    size_t per = 2 * (((size_t)rows_c * 2048 * 2 + 255) & ~(size_t)255);
    if (fixed + per <= ws_size) break;
    rows_c >>= 1;
  }
  unsigned short* Xcat = (unsigned short*)alloc((size_t)rows_c * 2048 * 2);
  unsigned short* S1c  = (unsigned short*)alloc((size_t)rows_c * 2048 * 2);

  // weight splits (once per call), 4 elem/thread
  k_split4<<<(2048 * 256 + 255) / 256, 256, 0, stream>>>((const float4*)W1, W1cat, 10,
                                                         (size_t)2048 * 256);
  k_split4<<<(2048 * 512 + 255) / 256, 256, 0, stream>>>((const float4*)W2, W2cat, 11,
                                                         (size_t)2048 * 512);
  k_split4<<<(512 * 512 + 255) / 256, 256, 0, stream>>>((const float4*)Wout, Wocat, 11,
                                                        (size_t)512 * 512);

  const int nch = 16384 / rows_c;
  for (int c = 0; c < nch; ++c) {
    k_split4<<<rows_c, 256, 0, stream>>>((const float4*)(x + (size_t)c * rows_c * 1024),
                                         Xcat, 10, (size_t)rows_c * 256);
    k_gemm_lif<1><<<dim3(rows_c / 256, 8), 512, 0, stream>>>(Xcat, W1cat, b1, S1c, 0);
    k_gemm_lif<2><<<dim3(rows_c / 256, 8), 512, 0, stream>>>(S1c, W2cat, b2, ACC,
                                                             c * (rows_c / 128));
  }
  k_init_out<<<256, 256, 0, stream>>>(out, bout);
  k_gemm3<<<dim3(1, 4, 16), 256, 0, stream>>>(ACC, Wocat, out);
}

// Round 13
// 321.941 us; speedup vs baseline: 3.2091x; 1.8074x over previous
//
#include <hip/hip_runtime.h>

// SpikingNetwork: B=128 T=128 I=1024 H1=2048 H2=2048 O=512
// R13 = R8 revert (empirical optimum). B-in-registers family (R9-R12)
//   invalidated: reg budget (acc 128 + B buffers + A pipeline > 256/wave)
//   forces either spill (R11) or uncovered L2 latency + vmcnt-mixing drains
//   (R12). R8 structure: 256x256 block tile, 8 waves of 128x64, BK=64,
//   2x64KB LDS dbuf (A+B), gld_lds staging (8/thread at p0, VMC(0)+BAR at
//   p2-end, ~3-phase lead), row-XOR swizzle, 4-phase lgkm-counted ds_read
//   pipeline (1 phase ahead), 2 barriers/tile, setprio around MFMA,
//   four-phase fused LIF epilogue via 64x258 f32 half-tile.
// Numerics: GEMM1 3-term split-bf16 (K'=3072), GEMM2 hi-only (K'=2048,
//   s1 binary exact), GEMM3 2-term split-K atomic. f32 accumulate.

typedef unsigned long long u64;
typedef __attribute__((ext_vector_type(4))) float f32x4;
typedef __attribute__((ext_vector_type(8))) short bf16x8;

__device__ __forceinline__ unsigned short f2bf(float f) {
  unsigned u = __float_as_uint(f);
  u += 0x7fff + ((u >> 16) & 1);   // RNE
  return (unsigned short)(u >> 16);
}
__device__ __forceinline__ float bf2f(unsigned short h) {
  return __uint_as_float(((unsigned)h) << 16);
}
__device__ __forceinline__ void gld_lds16(const unsigned short* g, unsigned short* l) {
  __builtin_amdgcn_global_load_lds((const __attribute__((address_space(1))) void*)g,
                                   (__attribute__((address_space(3))) void*)l, 16, 0, 0);
}

// src: R x K f32 (K = 1<<lgK) -> dst: R x 2K bf16 rows [hi | lo], 4 elem/thread
__global__ void k_split4(const float4* __restrict__ src, unsigned short* __restrict__ dst,
                         int lgK, size_t total4) {
  size_t i = (size_t)blockIdx.x * 256 + threadIdx.x;
  if (i >= total4) return;
  const int K = 1 << lgK;
  size_t e = i << 2;
  size_t r = e >> lgK;
  int k = (int)(e & (size_t)(K - 1));
  float4 f = src[i];
  unsigned short h0 = f2bf(f.x), h1 = f2bf(f.y), h2 = f2bf(f.z), h3 = f2bf(f.w);
  unsigned short l0 = f2bf(f.x - bf2f(h0)), l1 = f2bf(f.y - bf2f(h1));
  unsigned short l2 = f2bf(f.z - bf2f(h2)), l3 = f2bf(f.w - bf2f(h3));
  size_t o = (r << (lgK + 1)) + (size_t)k;
  *(u64*)(dst + o)     = (u64)h0 | ((u64)h1 << 16) | ((u64)h2 << 32) | ((u64)h3 << 48);
  *(u64*)(dst + o + K) = (u64)l0 | ((u64)l1 << 16) | ((u64)l2 << 32) | ((u64)l3 << 48);
}

// 4x ds_read_b128 from base + m*2048 (m-th 16-row fragment group)
#define DSR4(D, BASE)                                                          \
  do {                                                                         \
    asm volatile("ds_read_b128 %0, %1" : "=v"(D[0]) : "v"(BASE));              \
    asm volatile("ds_read_b128 %0, %1 offset:2048" : "=v"(D[1]) : "v"(BASE));  \
    asm volatile("ds_read_b128 %0, %1 offset:4096" : "=v"(D[2]) : "v"(BASE));  \
    asm volatile("ds_read_b128 %0, %1 offset:6144" : "=v"(D[3]) : "v"(BASE));  \
  } while (0)
#define WAITL(N)                                                               \
  do {                                                                         \
    asm volatile("s_waitcnt lgkmcnt(" #N ")" ::: "memory");                    \
    __builtin_amdgcn_sched_barrier(0);                                         \
  } while (0)
#define VM0() asm volatile("s_waitcnt vmcnt(0)" ::: "memory")
#define BAR() __builtin_amdgcn_s_barrier()
#define MFMA16(MH, AF, BG)                                                     \
  _Pragma("unroll")                                                            \
  for (int m = 0; m < 4; ++m)                                                  \
    _Pragma("unroll")                                                          \
    for (int n = 0; n < 4; ++n)                                                \
      acc[(MH)*4 + m][n] = __builtin_amdgcn_mfma_f32_16x16x32_bf16(            \
          AF[m], BG[n], acc[(MH)*4 + m][n], 0, 0, 0);

// Fused pipelined GEMM + LIF. Block tile 256x256 (2 batches' full time
// series x 256 cols). LAYER 1: NKT=48 (3-term); LAYER 2: NKT=32 (hi-only).
template <int LAYER>
__global__ __launch_bounds__(512, 2)
void k_gemm_lif(const unsigned short* __restrict__ A,
                const unsigned short* __restrict__ Bw,
                const float* __restrict__ bias,
                unsigned short* __restrict__ out, int b0) {
  __shared__ __align__(128) char lds[132096];  // 2x64KB slots; epi 128x258 f32
  const int NKT = (LAYER == 1) ? 48 : 32;
  const int ldB = (LAYER == 1) ? 2048 : 4096;
  const int tid  = threadIdx.x;
  const int lane = tid & 63;
  const int w    = tid >> 6;                 // 0..7
  const int wm = w >> 2, wn = w & 3;         // 2M x 4N waves
  const int wr = wm * 128, wc = wn * 64;     // wave tile 128x64
  const int lrow = lane & 15, t4 = lane >> 4;
  const int brow = blockIdx.x * 256, bcol = blockIdx.y * 256;

  f32x4 acc[8][4];
#pragma unroll
  for (int m = 0; m < 8; ++m)
#pragma unroll
    for (int n = 0; n < 4; ++n) acc[m][n] = (f32x4){0.f, 0.f, 0.f, 0.f};

  // Hoisted per-thread staging geometry (K-loop invariant). Global source
  // col pre-swizzled (chunk ^ row&7) so swizzled ds_read recovers linear K.
  int voffA[4], voffB[4];
  unsigned dstA[4], dstB[4];
#pragma unroll
  for (int j = 0; j < 4; ++j) {
    const int c = tid + j * 512;             // 2048 chunks each for A and B
    const int r = c >> 3;
    const int scol = ((c & 7) ^ (r & 7)) * 8;
    voffA[j] = (brow + r) * 2048 + scol;
    voffB[j] = (bcol + r) * ldB + scol;
    dstA[j] = (unsigned)c * 16;
    dstB[j] = 32768u + (unsigned)c * 16;
  }

  // Stage ALL of K-tile tt (A 256x64 + B 256x64, 8 chunks/thread) -> slot tt&1.
  auto stage_tile = [&](int tt) {
    if (tt >= NKT) return;
    const int kb = tt * 64;
    int aoff, boff;
    if (LAYER == 1) {
      aoff = (kb < 1024) ? kb : kb - 1024;    // [Xhi,Xhi,Xlo]
      boff = (kb < 2048) ? kb : kb - 2048;    // [W1hi,W1lo,W1hi]
    } else {
      aoff = kb;                               // binary S1 (K'=2048)
      boff = kb;                               // W2hi only
    }
    const unsigned short* Ap = A + aoff;       // wave-uniform pointer adds
    const unsigned short* Bp = Bw + boff;
    char* slot = lds + (tt & 1) * 65536;
#pragma unroll
    for (int j = 0; j < 4; ++j)
      gld_lds16(Ap + voffA[j], (unsigned short*)(slot + dstA[j]));
#pragma unroll
    for (int j = 0; j < 4; ++j)
      gld_lds16(Bp + voffB[j], (unsigned short*)(slot + dstB[j]));
  };

  // LDS fragment-read bases: row&7 == lrow&7 for every fragment row, so the
  // chunk index ch = (ks*4+t4)^(lrow&7) is per-lane constant per ks.
  const unsigned ldsb = (unsigned)(size_t)(__attribute__((address_space(3))) char*)lds;
  const unsigned cA   = (unsigned)((wr + lrow) * 128);
  const unsigned cB   = (unsigned)(32768 + (wc + lrow) * 128);
  const unsigned ch0  = (unsigned)(((t4) ^ (lrow & 7)) * 16);
  const unsigned ch1  = (unsigned)(((4 + t4) ^ (lrow & 7)) * 16);

  bf16x8 afA[4], afB[4], bgA[4], bgB[4];

  // prologue: tile 0 staged + landed; early-read p0 frags
  stage_tile(0);
  VM0();
  BAR();
  DSR4(afA, ldsb + cA + ch0);
  DSR4(bgA, ldsb + cB + ch0);

#pragma unroll 1
  for (int t = 0; t < NKT; ++t) {
    const unsigned sA  = ldsb + (unsigned)((t & 1) * 65536);
    const unsigned sAn = ldsb + (unsigned)(((t + 1) & 1) * 65536);
    // ---- phase 0: MFMA(MH0,ks0); read afB=MH1/ks0; stage t+1 ----
    stage_tile(t + 1);
    DSR4(afB, sA + cA + 8192 + ch0);
    WAITL(4);
    __builtin_amdgcn_s_setprio(1); MFMA16(0, afA, bgA); __builtin_amdgcn_s_setprio(0);
    // ---- phase 1: MFMA(MH1,ks0); read afA=MH0/ks1, bgB=ks1 ----
    DSR4(afA, sA + cA + ch1);
    DSR4(bgB, sA + cB + ch1);
    WAITL(8);
    __builtin_amdgcn_s_setprio(1); MFMA16(1, afB, bgA); __builtin_amdgcn_s_setprio(0);
    // ---- phase 2: MFMA(MH0,ks1); read afB=MH1/ks1 ----
    DSR4(afB, sA + cA + 8192 + ch1);
    WAITL(4);
    __builtin_amdgcn_s_setprio(1); MFMA16(0, afA, bgB); __builtin_amdgcn_s_setprio(0);
    VM0();   // stage(t+1) landed (issued ~3 phases ago); all-wave visible
    BAR();
    // ---- phase 3: MFMA(MH1,ks1); early-read t+1's p0 frags ----
    if (t + 1 < NKT) {
      DSR4(afA, sAn + cA + ch0);
      DSR4(bgA, sAn + cB + ch0);
      WAITL(8);
    } else {
      WAITL(0);
    }
    __builtin_amdgcn_s_setprio(1); MFMA16(1, afB, bgB); __builtin_amdgcn_s_setprio(0);
    BAR();   // tile boundary: slot-t reads lgkm-complete -> WAR safe
  }

  // ---- fused LIF epilogue: two 64-t halves, 128x258 f32 LDS tile ----
  float* Ct = (float*)lds;
  const int colT  = tid & 255;
  const int batch = tid >> 8;                // 2 batches x 256 cols = 512 scanners
  const float bs = bias[bcol + colT];
  float v = 0.f;
  int cnt = 0;
  unsigned short* sp = nullptr;
  if (LAYER == 1) sp = out + (size_t)(brow + batch * 128) * 2048 + bcol + colT;
#pragma unroll
  for (int h = 0; h < 2; ++h) {
    __syncthreads();
#pragma unroll
    for (int mm = 0; mm < 4; ++mm) {
      const int m = h * 4 + mm;              // frag m covers t = m*16..m*16+15
#pragma unroll
      for (int n = 0; n < 4; ++n) {
        const int lr  = wm * 64 + mm * 16 + t4 * 4;   // batch*64 + t-within-half
        const int col = wc + n * 16 + lrow;
#pragma unroll
        for (int r = 0; r < 4; ++r) Ct[(lr + r) * 258 + col] = acc[m][n][r];
      }
    }
    __syncthreads();
    if (LAYER == 1) {
#pragma unroll 4
      for (int tl = 0; tl < 64; ++tl) {
        const float xx = Ct[(batch * 64 + tl) * 258 + colT] + bs;
        v = 0.9f * xx + v - ((xx > 1.0f) ? 1.0f : 0.0f);
        sp[(size_t)(h * 64 + tl) * 2048] =
            (v > 1.0f) ? (unsigned short)0x3F80 : (unsigned short)0;
      }
    } else {
#pragma unroll 4
      for (int tl = 0; tl < 64; ++tl) {
        const float xx = Ct[(batch * 64 + tl) * 258 + colT] + bs;
        v = 0.9f * xx + v - ((xx > 1.0f) ? 1.0f : 0.0f);
        cnt += (v > 1.0f);
      }
    }
  }
  if (LAYER == 2)
    out[(size_t)(b0 + 2 * blockIdx.x + batch) * 2048 + bcol + colT] =
        f2bf((float)cnt * 0.0078125f);
}

// out(128x512) += ACC(128x2048 bf16) @ Wocat^T over K-slice z*256..+256, atomic
__global__ void k_gemm3(const unsigned short* __restrict__ A,
                        const unsigned short* __restrict__ B,
                        float* __restrict__ C) {
  __shared__ __align__(16) unsigned short Asm[128 * 64];
  __shared__ __align__(16) unsigned short Bsm[128 * 64];
  const int tid  = threadIdx.x;
  const int bcol = blockIdx.y * 128;
  const int k0   = blockIdx.z * 256;
  const int lane = tid & 63;
  const int w    = tid >> 6;
  const int wr = (w >> 1) * 64, wc = (w & 1) * 64;
  const int lrow = lane & 15, lk = (lane >> 4) * 8;

  f32x4 acc[4][4];
#pragma unroll
  for (int m = 0; m < 4; ++m)
#pragma unroll
    for (int n = 0; n < 4; ++n) acc[m][n] = (f32x4){0.f, 0.f, 0.f, 0.f};

  for (int kt = 0; kt < 4; ++kt) {
    const int kb = k0 + kt * 64;
#pragma unroll
    for (int i = 0; i < 4; ++i) {
      int c = tid + i * 256;
      int row = c >> 3, kc = (c & 7) * 8;
      gld_lds16(A + (size_t)row * 2048 + (kb & 2047) + kc, &Asm[c * 8]);
      gld_lds16(B + (size_t)(bcol + row) * 4096 + kb + kc, &Bsm[c * 8]);
    }
    __syncthreads();
#pragma unroll
    for (int ks = 0; ks < 2; ++ks) {
      bf16x8 af[4], bg[4];
#pragma unroll
      for (int m = 0; m < 4; ++m)
        af[m] = *(const bf16x8*)&Asm[(wr + m * 16 + lrow) * 64 + ks * 32 + lk];
#pragma unroll
      for (int n = 0; n < 4; ++n)
        bg[n] = *(const bf16x8*)&Bsm[(wc + n * 16 + lrow) * 64 + ks * 32 + lk];
#pragma unroll
      for (int m = 0; m < 4; ++m)
#pragma unroll
        for (int n = 0; n < 4; ++n)
          acc[m][n] = __builtin_amdgcn_mfma_f32_16x16x32_bf16(af[m], bg[n], acc[m][n], 0, 0, 0);
    }
    __syncthreads();
  }
#pragma unroll
  for (int m = 0; m < 4; ++m)
#pragma unroll
    for (int n = 0; n < 4; ++n) {
      int r0 = wr + m * 16 + (lane >> 4) * 4;
      int c0 = bcol + wc + n * 16 + (lane & 15);
#pragma unroll
      for (int r = 0; r < 4; ++r)
        atomicAdd(&C[(size_t)(r0 + r) * 512 + c0], acc[m][n][r]);
    }
}

__global__ void k_init_out(float* __restrict__ out, const float* __restrict__ bout) {
  int i = blockIdx.x * 256 + threadIdx.x;   // 128*512
  out[i] = bout[i & 511];
}

extern "C" void kernel_launch(void* const* d_in, const int* in_sizes, int n_in,
                              void* d_out, int out_size, void* d_ws, size_t ws_size,
                              hipStream_t stream) {
  const float* x    = (const float*)d_in[0];
  const float* W1   = (const float*)d_in[1];
  const float* b1   = (const float*)d_in[2];
  const float* W2   = (const float*)d_in[3];
  const float* b2   = (const float*)d_in[4];
  const float* Wout = (const float*)d_in[5];
  const float* bout = (const float*)d_in[6];
  float* out = (float*)d_out;
  (void)in_sizes; (void)n_in; (void)out_size;

  char* ws = (char*)d_ws;
  size_t off = 0;
  auto alloc = [&](size_t bytes) -> void* {
    void* p = ws + off;
    off += (bytes + 255) & ~(size_t)255;
    return p;
  };
  unsigned short* W1cat = (unsigned short*)alloc((size_t)2048 * 2048 * 2);  // 8 MiB
  unsigned short* W2cat = (unsigned short*)alloc((size_t)2048 * 4096 * 2);  // 16 MiB
  unsigned short* Wocat = (unsigned short*)alloc((size_t)512 * 4096 * 2);   // 4 MiB
  unsigned short* ACC   = (unsigned short*)alloc((size_t)128 * 2048 * 2);   // 0.5 MiB
  const size_t fixed = off;

  // largest row-chunk (multiple of 1024) whose Xcat+S1 fit in ws
  int rows_c = 16384;
  while (rows_c > 1024) {
    size_t per = 2 * (((size_t)rows_c * 2048 * 2 + 255) & ~(size_t)255);
    if (fixed + per <= ws_size) break;
    rows_c >>= 1;
  }
  unsigned short* Xcat = (unsigned short*)alloc((size_t)rows_c * 2048 * 2);
  unsigned short* S1c  = (unsigned short*)alloc((size_t)rows_c * 2048 * 2);

  // weight splits (once per call), 4 elem/thread
  k_split4<<<(2048 * 256 + 255) / 256, 256, 0, stream>>>((const float4*)W1, W1cat, 10,
                                                         (size_t)2048 * 256);
  k_split4<<<(2048 * 512 + 255) / 256, 256, 0, stream>>>((const float4*)W2, W2cat, 11,
                                                         (size_t)2048 * 512);
  k_split4<<<(512 * 512 + 255) / 256, 256, 0, stream>>>((const float4*)Wout, Wocat, 11,
                                                        (size_t)512 * 512);

  const int nch = 16384 / rows_c;
  for (int c = 0; c < nch; ++c) {
    k_split4<<<rows_c, 256, 0, stream>>>((const float4*)(x + (size_t)c * rows_c * 1024),
                                         Xcat, 10, (size_t)rows_c * 256);
    k_gemm_lif<1><<<dim3(rows_c / 256, 8), 512, 0, stream>>>(Xcat, W1cat, b1, S1c, 0);
    k_gemm_lif<2><<<dim3(rows_c / 256, 8), 512, 0, stream>>>(S1c, W2cat, b2, ACC,
                                                             c * (rows_c / 128));
  }
  k_init_out<<<256, 256, 0, stream>>>(out, bout);
  k_gemm3<<<dim3(1, 4, 16), 256, 0, stream>>>(ACC, Wocat, out);
}